// Round 1
// baseline (902.391 us; speedup 1.0000x reference)
//
#include <hip/hip_runtime.h>
#include <math.h>

// Geometry constants (from the reference)
#define TH 8192        // FULL_SIZE[1]  (H of sampled image)
#define TW 128         // FULL_SIZE[0]  (W of sampled image)
#define TC 32          // OUT_CHANNELS
#define PLANE (TH * TW)   // 1048576 elements per channel plane

// ---------------------------------------------------------------------------
// Transpose (C,H,W) -> (H,W,C).  One block per y-row. 16.5 KB LDS tile.
// Reads coalesced 512B runs per channel, writes fully coalesced 16 KB row.
// ---------------------------------------------------------------------------
__global__ __launch_bounds__(256) void transpose_kernel(
        const float* __restrict__ in, float* __restrict__ out) {
    __shared__ float lds[TW * 33];   // pad 32->33 to kill bank conflicts
    const int y = blockIdx.x;
    const int t = threadIdx.x;
    const float* src = in + (size_t)y * TW;
#pragma unroll
    for (int i = 0; i < 16; ++i) {
        int l = i * 256 + t;          // 0..4095
        int c = l >> 7;               // channel
        int x = l & 127;              // column
        lds[x * 33 + c] = src[(size_t)c * PLANE + x];
    }
    __syncthreads();
    float* dst = out + (size_t)y * (TW * TC);
#pragma unroll
    for (int i = 0; i < 16; ++i) {
        int l = i * 256 + t;          // linear (x,c) output index
        int x = l >> 5;
        int c = l & 31;
        dst[l] = lds[x * 33 + c];
    }
}

// ---------------------------------------------------------------------------
// Sampling kernel. 8 lanes per point; each lane owns 4 consecutive channels.
// TRANSPOSED=true reads the (H,W,C) scratch layout with float4 loads.
// ---------------------------------------------------------------------------
template <bool TRANSPOSED>
__global__ __launch_bounds__(256) void sample_kernel(
        const float* __restrict__ xin, const float* __restrict__ tens,
        float* __restrict__ out, int n) {
    const int tid = blockIdx.x * 256 + threadIdx.x;
    const int p  = tid >> 3;          // point index
    if (p >= n) return;
    const int c4 = tid & 7;           // which float4 group of channels

    const float px = xin[p * 3 + 0];
    const float py = xin[p * 3 + 1];
    const float pz = xin[p * 3 + 2];

    // voxel index: floor(clip(x,0,1)*4) clipped to [0,3]
    float v0 = fminf(floorf(fminf(fmaxf(px, 0.f), 1.f) * 4.f), 3.f);
    float v1 = fminf(floorf(fminf(fmaxf(py, 0.f), 1.f) * 4.f), 3.f);
    float v2 = fminf(floorf(fminf(fmaxf(pz, 0.f), 1.f) * 4.f), 3.f);
    float voxel = v2 * 16.f + v1 * 4.f + v0;

    const bool mask = !(px < 0.f || px > 1.f || py < 0.f || py > 1.f);

    // xm = remainder(xn*512, 128); positive operands -> fmodf matches jnp
    float xm0 = fmodf(px * 512.f, 128.f);
    float xm1 = fmodf(py * 512.f, 128.f);

    // replicate the reference's grid->pixel arithmetic literally
    float gx = xm0 / 128.f * 2.f - 1.f;
    float gy = (xm1 + voxel * 128.f) / 8192.f * 2.f - 1.f;
    if (!mask) { gx = 1e8f; gy = 1e8f; }
    float ix = ((gx + 1.f) * (float)TW - 1.f) * 0.5f;
    float iy = ((gy + 1.f) * (float)TH - 1.f) * 0.5f;

    float ix0 = floorf(ix), iy0 = floorf(iy);
    float wx = ix - ix0,    wy = iy - iy0;
    float ix1f = ix0 + 1.f, iy1f = iy0 + 1.f;

    // per-corner validity folded into weights; indices clamped for safe loads
    float vx0 = (ix0  >= 0.f && ix0  <= (float)(TW - 1)) ? 1.f : 0.f;
    float vx1 = (ix1f >= 0.f && ix1f <= (float)(TW - 1)) ? 1.f : 0.f;
    float vy0 = (iy0  >= 0.f && iy0  <= (float)(TH - 1)) ? 1.f : 0.f;
    float vy1 = (iy1f >= 0.f && iy1f <= (float)(TH - 1)) ? 1.f : 0.f;

    int xi0 = (int)fminf(fmaxf(ix0,  0.f), (float)(TW - 1));
    int xi1 = (int)fminf(fmaxf(ix1f, 0.f), (float)(TW - 1));
    int yi0 = (int)fminf(fmaxf(iy0,  0.f), (float)(TH - 1));
    int yi1 = (int)fminf(fmaxf(iy1f, 0.f), (float)(TH - 1));

    float w00 = (1.f - wx) * (1.f - wy) * vx0 * vy0;
    float w01 = wx * (1.f - wy) * vx1 * vy0;
    float w10 = (1.f - wx) * wy * vx0 * vy1;
    float w11 = wx * wy * vx1 * vy1;

    float4 A, B, Cv, D;
    if (TRANSPOSED) {
        const float4* t4 = (const float4*)tens;   // (H, W, C) layout, 8 float4 per (y,x)
        A  = t4[(yi0 * TW + xi0) * 8 + c4];
        B  = t4[(yi0 * TW + xi1) * 8 + c4];
        Cv = t4[(yi1 * TW + xi0) * 8 + c4];
        D  = t4[(yi1 * TW + xi1) * 8 + c4];
    } else {
        const int cb = c4 * 4;
        const float* t0 = tens + (size_t)cb * PLANE;
        int o00 = yi0 * TW + xi0, o01 = yi0 * TW + xi1;
        int o10 = yi1 * TW + xi0, o11 = yi1 * TW + xi1;
        A  = make_float4(t0[o00], t0[PLANE + o00], t0[2 * PLANE + o00], t0[3 * PLANE + o00]);
        B  = make_float4(t0[o01], t0[PLANE + o01], t0[2 * PLANE + o01], t0[3 * PLANE + o01]);
        Cv = make_float4(t0[o10], t0[PLANE + o10], t0[2 * PLANE + o10], t0[3 * PLANE + o10]);
        D  = make_float4(t0[o11], t0[PLANE + o11], t0[2 * PLANE + o11], t0[3 * PLANE + o11]);
    }

    float4 r;
    r.x = w00 * A.x + w01 * B.x + w10 * Cv.x + w11 * D.x;
    r.y = w00 * A.y + w01 * B.y + w10 * Cv.y + w11 * D.y;
    r.z = w00 * A.z + w01 * B.z + w10 * Cv.z + w11 * D.z;
    r.w = w00 * A.w + w01 * B.w + w10 * Cv.w + w11 * D.w;

    ((float4*)out)[(size_t)p * 8 + c4] = r;   // (N, 32) output, fully coalesced
}

extern "C" void kernel_launch(void* const* d_in, const int* in_sizes, int n_in,
                              void* d_out, int out_size, void* d_ws, size_t ws_size,
                              hipStream_t stream) {
    const float* x      = (const float*)d_in[0];
    const float* tensor = (const float*)d_in[1];
    float* out = (float*)d_out;
    const int n = in_sizes[0] / 3;            // 4,000,000 points

    const size_t need = (size_t)TC * TH * TW * sizeof(float);  // 128 MiB
    const int threads = n * 8;
    const int blocks  = (threads + 255) / 256;

    if (ws_size >= need) {
        float* tt = (float*)d_ws;
        transpose_kernel<<<TH, 256, 0, stream>>>(tensor, tt);
        sample_kernel<true><<<blocks, 256, 0, stream>>>(x, tt, out, n);
    } else {
        // scratch too small: sample directly from (C,H,W) layout (slower, correct)
        sample_kernel<false><<<blocks, 256, 0, stream>>>(x, tensor, out, n);
    }
}